// Round 7
// baseline (24149.496 us; speedup 1.0000x reference)
//
#include <hip/hip_runtime.h>
#include <stdint.h>

// BiGRU scan, H=1024. Round 7 = Round 6 design, deadlock fixed.
//  - R6 bug: pubf[8] polled at lane&7 but only 4 waves exist -> entries 4..7
//    stayed -1 -> wave0 spun forever at t=0 (grid deadlock). Fix: pubf[4],
//    poll lane&3. Also: publish ack (vmcnt(0)) moved BEFORE out-stores so the
//    counter add isn't delayed by the scattered-store drain.
//  - Design: producers publish untagged 4B x values (8B store/wave), ack,
//    signal LDS; wave0 does ONE atomicAdd/block to 1-of-8 padded counters.
//    Consumers: wave0 polls the 8 counter lines (one coalesced instr/round),
//    then the block does ONE coalesced 4KB sweep (data final, no retries).

#define H    1024
#define HH   1025
#define N3   3075
#define TQ   512
#define TP   4096
#define MTOT 4608
#define GH_ELEMS ((size_t)MTOT * (size_t)N3)
#define NBLK_P 128
#define NBLK_Q 128
#define CLS   64          // ints per counter slot (256B padding)

typedef unsigned long long ull;
typedef unsigned int u32x2 __attribute__((ext_vector_type(2)));
typedef unsigned int u32x4 __attribute__((ext_vector_type(4)));

__device__ __forceinline__ float sigm(float x) { return 1.f / (1.f + __expf(-x)); }
__device__ __forceinline__ float fast_tanh(float x) {
    float e = __expf(2.f * x);
    return (e - 1.f) / (e + 1.f);
}

// ---------------------------------------------------------------------------
// gh GEMM (unchanged): gh[dir][m][r] = h0[m][dir] . Whh_dir[r] + bhh_dir[r]
// ---------------------------------------------------------------------------
__global__ __launch_bounds__(256, 2) void gh_gemm(
    const float* __restrict__ eq, const float* __restrict__ ep,
    const float* __restrict__ fs, const float* __restrict__ fe,
    const float* __restrict__ Whh_f, const float* __restrict__ bhh_f,
    const float* __restrict__ Whh_b, const float* __restrict__ bhh_b,
    float* __restrict__ ghf, float* __restrict__ ghb)
{
    const int dir = blockIdx.z;
    const float* W  = dir ? Whh_b : Whh_f;
    const float* bh = dir ? bhh_b : bhh_f;
    float* gh = dir ? ghb : ghf;
    const int n0 = blockIdx.x * 128;
    const int m0 = blockIdx.y * 128;

    __shared__ float As[16][132];
    __shared__ float Bs[16][132];

    float acc[8][8];
#pragma unroll
    for (int i = 0; i < 8; i++)
#pragma unroll
        for (int j = 0; j < 8; j++) acc[i][j] = 0.f;

    const int tid = threadIdx.x;
    const int tx = tid & 15, ty = tid >> 4;

    for (int k0 = 0; k0 < HH; k0 += 16) {
#pragma unroll
        for (int u = 0; u < 8; u++) {
            int lin = tid + 256 * u;
            int k = lin & 15;
            int m = lin >> 4;
            int gm = m0 + m;
            int gk = k0 + k;
            float v = 0.f;
            if (gk < HH) {
                bool isq = gm < TQ;
                const float* e = isq ? eq : ep;
                int t = isq ? gm : gm - TQ;
                if (dir == 0)            v = e[(size_t)t * 2048 + gk];
                else if (gk < 1023)      v = e[(size_t)t * 2048 + 1025 + gk];
                else if (!isq)           v = (gk == 1023) ? fs[t] : fe[t];
            }
            As[k][m] = v;
        }
#pragma unroll
        for (int u = 0; u < 8; u++) {
            int lin = tid + 256 * u;
            int k = lin & 15;
            int r = lin >> 4;
            int gr = n0 + r, gk = k0 + k;
            Bs[k][r] = (gr < N3 && gk < HH) ? W[(size_t)gr * HH + gk] : 0.f;
        }
        __syncthreads();
#pragma unroll
        for (int kk = 0; kk < 16; kk++) {
            float4 a0 = *(const float4*)&As[kk][ty * 4];
            float4 a1 = *(const float4*)&As[kk][64 + ty * 4];
            float4 b0 = *(const float4*)&Bs[kk][tx * 4];
            float4 b1 = *(const float4*)&Bs[kk][64 + tx * 4];
            float a[8] = {a0.x, a0.y, a0.z, a0.w, a1.x, a1.y, a1.z, a1.w};
            float b[8] = {b0.x, b0.y, b0.z, b0.w, b1.x, b1.y, b1.z, b1.w};
#pragma unroll
            for (int i = 0; i < 8; i++)
#pragma unroll
                for (int j = 0; j < 8; j++) acc[i][j] += a[i] * b[j];
        }
        __syncthreads();
    }
#pragma unroll
    for (int i = 0; i < 8; i++) {
        int gm = m0 + ((i < 4) ? (ty * 4 + i) : (64 + ty * 4 + i - 4));
#pragma unroll
        for (int j = 0; j < 8; j++) {
            int gr = n0 + ((j < 4) ? (tx * 4 + j) : (64 + tx * 4 + j - 4));
            if (gr < N3) gh[(size_t)gm * N3 + gr] = acc[i][j] + bh[gr];
        }
    }
}

// ---------------------------------------------------------------------------
// Persistent scan.
// ---------------------------------------------------------------------------
__global__ __launch_bounds__(256, 1) void bigru_scan(
    const float* __restrict__ eq, const float* __restrict__ ep,
    const float* __restrict__ fs,
    const float* __restrict__ Wih_f, const float* __restrict__ bih_f,
    const float* __restrict__ Wih_b, const float* __restrict__ bih_b,
    const float* __restrict__ ghf,   // ghb contiguous at ghf + GH_ELEMS
    float* __restrict__ commx,       // [chain][parity][1024] float x slots
    int*   __restrict__ ctr,         // [chain][parity][8] counters, CLS-padded
    float* __restrict__ out)         // h_q (512*2048) then h_p (4096*2048)
{
    __shared__ float xs[1024];
    __shared__ int sflag;
    __shared__ int pubf[4];

    const int tid  = threadIdx.x;
    const int wave = tid >> 6;
    const int lane = tid & 63;
    const bool isP = (int)blockIdx.x < NBLK_P;
    const int  blk = isP ? (int)blockIdx.x : (int)blockIdx.x - NBLK_P;
    const int  u0  = __builtin_amdgcn_readfirstlane(blk * 8 + wave * 2);
    const bool extra = (u0 == 1022);
    const int  nT  = isP ? TP : TQ;
    const float* emb = isP ? ep : eq;
    const float* fsp = isP ? fs : nullptr;
    const int chain  = isP ? 0 : 1;
    float* dataB = commx + (size_t)chain * 2048;         // [parity][1024]
    int*   ctrB  = ctr + (size_t)chain * 2 * 8 * CLS;    // [parity][8*CLS]
    float* outb  = isP ? (out + (size_t)TQ * 2048) : out;
    const int ghTok0 = isP ? TQ : 0;

    if (tid == 0) sflag = -1;
    if (tid < 4) pubf[tid] = -1;
    __syncthreads();

    // elems: e0=(0,u0); e1= u0? (1,u0-1):(0,1024); e2=(0,u0+1); e3=(1,u0)
    int dirE[4], rowE[4];
    bool stE1;
    dirE[0] = 0; rowE[0] = u0;
    if (u0 == 0) { dirE[1] = 0; rowE[1] = 1024;   stE1 = false; }
    else         { dirE[1] = 1; rowE[1] = u0 - 1; stE1 = true;  }
    dirE[2] = 0; rowE[2] = u0 + 1;
    dirE[3] = 1; rowE[3] = u0;

    // register-resident Wih rows (k-split: lane l holds k = 4l + 256i + m)
    float wreg[12][16], breg[12];
#pragma unroll
    for (int e = 0; e < 4; e++) {
        const float* W  = dirE[e] ? Wih_b : Wih_f;
        const float* bb = dirE[e] ? bih_b : bih_f;
#pragma unroll
        for (int g = 0; g < 3; g++) {
            const float* wr = W + (size_t)(g * HH + rowE[e]) * H;
#pragma unroll
            for (int i = 0; i < 4; i++) {
                float4 w4 = *(const float4*)(wr + i * 256 + lane * 4);
                wreg[e*3+g][i*4+0] = w4.x; wreg[e*3+g][i*4+1] = w4.y;
                wreg[e*3+g][i*4+2] = w4.z; wreg[e*3+g][i*4+3] = w4.w;
            }
            breg[e*3+g] = bb[g * HH + rowE[e]];
        }
    }
    float wregX[3][16], bregX[3];
    if (extra) {
#pragma unroll
        for (int g = 0; g < 3; g++) {
            const float* wr = Wih_b + (size_t)(g * HH + 1023) * H;
#pragma unroll
            for (int i = 0; i < 4; i++) {
                float4 w4 = *(const float4*)(wr + i * 256 + lane * 4);
                wregX[g][i*4+0] = w4.x; wregX[g][i*4+1] = w4.y;
                wregX[g][i*4+2] = w4.z; wregX[g][i*4+3] = w4.w;
            }
            bregX[g] = bih_b[g * HH + 1023];
        }
    }

    // gh/h0 offsets (wave-uniform values)
    size_t ghoff[4];
    int h0col[4];
#pragma unroll
    for (int e = 0; e < 4; e++) {
        ghoff[e] = (dirE[e] ? GH_ELEMS : (size_t)0) + (size_t)rowE[e];
        h0col[e] = dirE[e] ? (1025 + rowE[e]) : rowE[e];
    }
    const size_t ghoffX = GH_ELEMS + 1023;

    auto ldgh = [&](int tok, float gh[12], float h0[4], float ghX[3], float& h0X) {
        size_t tb = (size_t)(ghTok0 + tok) * N3;
#pragma unroll
        for (int e = 0; e < 4; e++) {
#pragma unroll
            for (int g = 0; g < 3; g++)
                gh[e*3+g] = ghf[ghoff[e] + tb + (size_t)g * HH];
            h0[e] = emb[(size_t)tok * 2048 + h0col[e]];
        }
        if (extra) {
#pragma unroll
            for (int g = 0; g < 3; g++) ghX[g] = ghf[ghoffX + tb + (size_t)g * HH];
            h0X = fsp ? fsp[tok] : 0.f;
        }
    };

    float ghc[12], h0c[4], ghcX[3]; float h0X = 0.f;
    float ghn[12], h0n[4], ghnX[3]; float h0nX = 0.f;
    ldgh(0, ghc, h0c, ghcX, h0X);

    for (int t = 0; t < nT; t++) {
        float x[16];
        if (t) {
            const int rpar = (t + 1) & 1;                 // bank holding x_t
            const int target = 16 * (((t - 1) >> 1) + 1); // epoch target
            if (wave == 0) {
                int* cp = ctrB + rpar * 8 * CLS + (lane & 7) * CLS;
                for (;;) {
                    int v = __hip_atomic_load(cp, __ATOMIC_RELAXED, __HIP_MEMORY_SCOPE_AGENT);
                    if (__all(v >= target)) break;
                }
                __asm__ volatile("" ::: "memory");
                if (lane == 0) *(volatile int*)&sflag = t;
            } else {
                while (*(volatile int*)&sflag < t) {}
            }
            // one-shot coalesced sweep: data is final, no retries
            const float* db = dataB + (size_t)rpar * 1024;
            u32x4 dv;
            asm volatile(
                "global_load_dwordx4 %0, %1, off sc0 sc1\n\t"
                "s_waitcnt vmcnt(0)"
                : "=v"(dv) : "v"(db + 4 * tid) : "memory");
            ((u32x4*)xs)[tid] = dv;
            __syncthreads();
#pragma unroll
            for (int i = 0; i < 4; i++) {
                float4 xv = *(const float4*)&xs[i * 256 + 4 * lane];
                x[i*4+0] = xv.x; x[i*4+1] = xv.y; x[i*4+2] = xv.z; x[i*4+3] = xv.w;
            }
        } else {
#pragma unroll
            for (int k = 0; k < 16; k++) x[k] = 0.f;
        }

        // dots + butterfly reduce
        float acc[12], accX[3];
#pragma unroll
        for (int r = 0; r < 12; r++) {
            float s = 0.f;
#pragma unroll
            for (int i = 0; i < 16; i++) s += wreg[r][i] * x[i];
            acc[r] = s;
        }
        if (extra) {
#pragma unroll
            for (int g = 0; g < 3; g++) {
                float s = 0.f;
#pragma unroll
                for (int i = 0; i < 16; i++) s += wregX[g][i] * x[i];
                accX[g] = s;
            }
        }
#pragma unroll
        for (int off = 32; off > 0; off >>= 1) {
#pragma unroll
            for (int r = 0; r < 12; r++) acc[r] += __shfl_xor(acc[r], off, 64);
            if (extra) {
#pragma unroll
                for (int g = 0; g < 3; g++) accX[g] += __shfl_xor(accX[g], off, 64);
            }
        }

        // gates (redundant across lanes)
        float y[4];
#pragma unroll
        for (int e = 0; e < 4; e++) {
            float rr = sigm(acc[e*3+0] + breg[e*3+0] + ghc[e*3+0]);
            float zz = sigm(acc[e*3+1] + breg[e*3+1] + ghc[e*3+1]);
            float nn = fast_tanh(acc[e*3+2] + breg[e*3+2] + rr * ghc[e*3+2]);
            y[e] = (1.f - zz) * nn + zz * h0c[e];
        }

        // publish x slots; ack BEFORE out-stores; signal; then out stores
        if (lane == 0) {
            float* ps = dataB + (size_t)(t & 1) * 1024 + u0;
            u32x2 pv;
            pv[0] = __float_as_uint(y[0] + y[1]);
            pv[1] = __float_as_uint(y[2] + y[3]);
            asm volatile(
                "global_store_dwordx2 %0, %1, off sc0 sc1\n\t"
                "s_waitcnt vmcnt(0)"
                :: "v"(ps), "v"(pv) : "memory");
            *(volatile int*)&pubf[wave] = t;

            size_t ob = (size_t)t * 2048;
            outb[ob + u0]        = y[0];
            outb[ob + u0 + 1]    = y[2];
            if (stE1) outb[ob + 1023 + u0] = y[1];
            outb[ob + 1024 + u0] = y[3];
            if (extra) {
                float rr = sigm(accX[0] + bregX[0] + ghcX[0]);
                float zz = sigm(accX[1] + bregX[1] + ghcX[1]);
                float nn = fast_tanh(accX[2] + bregX[2] + rr * ghcX[2]);
                outb[ob + 2047] = (1.f - zz) * nn + zz * h0X;
            }
        }

        // prefetch next gh/h0 (latency hidden by inter-step wait)
        const bool more = (t + 1) < nT;
        if (more) ldgh(t + 1, ghn, h0n, ghnX, h0nX);

        // block-completion counter add (wave 0; 4 waves per block)
        if (wave == 0) {
            volatile int* pf = pubf;
            for (;;) {
                int v = pf[lane & 3];
                if (__all(v >= t)) break;
            }
            if (lane == 0) {
                int* ca = ctrB + (t & 1) * 8 * CLS + (blk & 7) * CLS;
                (void)__hip_atomic_fetch_add(ca, 1, __ATOMIC_RELAXED, __HIP_MEMORY_SCOPE_AGENT);
            }
        }

        if (more) {
#pragma unroll
            for (int r = 0; r < 12; r++) ghc[r] = ghn[r];
#pragma unroll
            for (int e = 0; e < 4; e++) h0c[e] = h0n[e];
#pragma unroll
            for (int g = 0; g < 3; g++) ghcX[g] = ghnX[g];
            h0X = h0nX;
        }
    }
}

extern "C" void kernel_launch(void* const* d_in, const int* in_sizes, int n_in,
                              void* d_out, int out_size, void* d_ws, size_t ws_size,
                              hipStream_t stream) {
    const float* eq    = (const float*)d_in[0];
    const float* ep    = (const float*)d_in[1];
    const float* fs    = (const float*)d_in[2];
    const float* fe    = (const float*)d_in[3];
    const float* Wih_f = (const float*)d_in[4];
    const float* Whh_f = (const float*)d_in[5];
    const float* bih_f = (const float*)d_in[6];
    const float* bhh_f = (const float*)d_in[7];
    const float* Wih_b = (const float*)d_in[8];
    const float* Whh_b = (const float*)d_in[9];
    const float* bih_b = (const float*)d_in[10];
    const float* bhh_b = (const float*)d_in[11];
    float* out = (float*)d_out;

    float* ghf = (float*)d_ws;
    float* ghb = ghf + GH_ELEMS;
    size_t off = ((2 * GH_ELEMS * sizeof(float)) + 4095) & ~(size_t)4095;
    float* commx = (float*)((char*)d_ws + off);            // 2*2*1024 floats = 16KB
    int*   ctr   = (int*)((char*)d_ws + off + 16384);      // 2*2*8*CLS ints = 8KB

    hipMemsetAsync(ctr, 0, (size_t)2 * 2 * 8 * CLS * sizeof(int), stream);

    dim3 ggrid((N3 + 127) / 128, MTOT / 128, 2);
    gh_gemm<<<ggrid, 256, 0, stream>>>(eq, ep, fs, fe, Whh_f, bhh_f, Whh_b, bhh_b, ghf, ghb);

    bigru_scan<<<dim3(NBLK_P + NBLK_Q), dim3(256), 0, stream>>>(
        eq, ep, fs, Wih_f, bih_f, Wih_b, bih_b, ghf, commx, ctr, out);
}

// Round 8
// 20724.135 us; speedup vs baseline: 1.1653x; 1.1653x over previous
//
#include <hip/hip_runtime.h>
#include <stdint.h>

// BiGRU scan, H=1024. Round 8: minimum-hop dataflow scan.
// Lesson R2..R7: step time = (#serialized global hops) x (effective RT ~2.5k
// cyc under load). Minimum structure = publish (no ack) -> poll data directly
// (tags) -> compute. This is R2's topology with:
//  - 1024 pair-fused tagged slots (R4 mapping), 2 x 16B granule polls/thread
//    (one s_waitcnt per retry round), exactly covering the vector.
//  - gh/h0 prefetch issued AFTER detect+syncthreads (hides under compute,
//    never FIFO-pollutes a retry vmcnt wait).
//  - publish: one 16B sc0 sc1 store per wave, NO ack.
//  - q-chain on its own 128 blocks; 256 blocks total, 1/CU.
//  - LDS x double-buffered by parity.

#define H    1024
#define HH   1025
#define N3   3075
#define TQ   512
#define TP   4096
#define MTOT 4608
#define GH_ELEMS ((size_t)MTOT * (size_t)N3)
#define NBLK_P 128
#define NBLK_Q 128

typedef unsigned long long ull;
typedef unsigned int u32x4 __attribute__((ext_vector_type(4)));

__device__ __forceinline__ float sigm(float x) { return 1.f / (1.f + __expf(-x)); }
__device__ __forceinline__ float fast_tanh(float x) {
    float e = __expf(2.f * x);
    return (e - 1.f) / (e + 1.f);
}

__device__ __forceinline__ void load2t(const ull* p0, const ull* p1, u32x4& a, u32x4& b) {
    asm volatile(
        "global_load_dwordx4 %0, %2, off sc0 sc1\n\t"
        "global_load_dwordx4 %1, %3, off sc0 sc1\n\t"
        "s_waitcnt vmcnt(0)"
        : "=&v"(a), "=&v"(b) : "v"(p0), "v"(p1) : "memory");
}
__device__ __forceinline__ void store1g(ull* p, u32x4 v) {
    asm volatile("global_store_dwordx4 %0, %1, off sc0 sc1" :: "v"(p), "v"(v) : "memory");
}

// ---------------------------------------------------------------------------
// gh GEMM (unchanged): gh[dir][m][r] = h0[m][dir] . Whh_dir[r] + bhh_dir[r]
// ---------------------------------------------------------------------------
__global__ __launch_bounds__(256, 2) void gh_gemm(
    const float* __restrict__ eq, const float* __restrict__ ep,
    const float* __restrict__ fs, const float* __restrict__ fe,
    const float* __restrict__ Whh_f, const float* __restrict__ bhh_f,
    const float* __restrict__ Whh_b, const float* __restrict__ bhh_b,
    float* __restrict__ ghf, float* __restrict__ ghb)
{
    const int dir = blockIdx.z;
    const float* W  = dir ? Whh_b : Whh_f;
    const float* bh = dir ? bhh_b : bhh_f;
    float* gh = dir ? ghb : ghf;
    const int n0 = blockIdx.x * 128;
    const int m0 = blockIdx.y * 128;

    __shared__ float As[16][132];
    __shared__ float Bs[16][132];

    float acc[8][8];
#pragma unroll
    for (int i = 0; i < 8; i++)
#pragma unroll
        for (int j = 0; j < 8; j++) acc[i][j] = 0.f;

    const int tid = threadIdx.x;
    const int tx = tid & 15, ty = tid >> 4;

    for (int k0 = 0; k0 < HH; k0 += 16) {
#pragma unroll
        for (int u = 0; u < 8; u++) {
            int lin = tid + 256 * u;
            int k = lin & 15;
            int m = lin >> 4;
            int gm = m0 + m;
            int gk = k0 + k;
            float v = 0.f;
            if (gk < HH) {
                bool isq = gm < TQ;
                const float* e = isq ? eq : ep;
                int t = isq ? gm : gm - TQ;
                if (dir == 0)            v = e[(size_t)t * 2048 + gk];
                else if (gk < 1023)      v = e[(size_t)t * 2048 + 1025 + gk];
                else if (!isq)           v = (gk == 1023) ? fs[t] : fe[t];
            }
            As[k][m] = v;
        }
#pragma unroll
        for (int u = 0; u < 8; u++) {
            int lin = tid + 256 * u;
            int k = lin & 15;
            int r = lin >> 4;
            int gr = n0 + r, gk = k0 + k;
            Bs[k][r] = (gr < N3 && gk < HH) ? W[(size_t)gr * HH + gk] : 0.f;
        }
        __syncthreads();
#pragma unroll
        for (int kk = 0; kk < 16; kk++) {
            float4 a0 = *(const float4*)&As[kk][ty * 4];
            float4 a1 = *(const float4*)&As[kk][64 + ty * 4];
            float4 b0 = *(const float4*)&Bs[kk][tx * 4];
            float4 b1 = *(const float4*)&Bs[kk][64 + tx * 4];
            float a[8] = {a0.x, a0.y, a0.z, a0.w, a1.x, a1.y, a1.z, a1.w};
            float b[8] = {b0.x, b0.y, b0.z, b0.w, b1.x, b1.y, b1.z, b1.w};
#pragma unroll
            for (int i = 0; i < 8; i++)
#pragma unroll
                for (int j = 0; j < 8; j++) acc[i][j] += a[i] * b[j];
        }
        __syncthreads();
    }
#pragma unroll
    for (int i = 0; i < 8; i++) {
        int gm = m0 + ((i < 4) ? (ty * 4 + i) : (64 + ty * 4 + i - 4));
#pragma unroll
        for (int j = 0; j < 8; j++) {
            int gr = n0 + ((j < 4) ? (tx * 4 + j) : (64 + tx * 4 + j - 4));
            if (gr < N3) gh[(size_t)gm * N3 + gr] = acc[i][j] + bh[gr];
        }
    }
}

// ---------------------------------------------------------------------------
// Persistent scan. Blocks [0,128): p-chain; [128,256): q-chain.
// ---------------------------------------------------------------------------
__global__ __launch_bounds__(256, 1) void bigru_scan(
    const float* __restrict__ eq, const float* __restrict__ ep,
    const float* __restrict__ fs,
    const float* __restrict__ Wih_f, const float* __restrict__ bih_f,
    const float* __restrict__ Wih_b, const float* __restrict__ bih_b,
    const float* __restrict__ ghf,   // ghb contiguous at ghf + GH_ELEMS
    ull* __restrict__ comm,          // [chain][parity][1024] tagged 8B slots
    float* __restrict__ out)         // h_q (512*2048) then h_p (4096*2048)
{
    __shared__ float xs[2][1024];

    const int tid  = threadIdx.x;
    const int wave = tid >> 6;
    const int lane = tid & 63;
    const bool isP = (int)blockIdx.x < NBLK_P;
    const int  blk = isP ? (int)blockIdx.x : (int)blockIdx.x - NBLK_P;
    const int  u0  = __builtin_amdgcn_readfirstlane(blk * 8 + wave * 2);
    const bool extra = (u0 == 1022);
    const int  nT  = isP ? TP : TQ;
    const float* emb = isP ? ep : eq;
    const float* fsp = isP ? fs : nullptr;
    ull*   cm   = comm + (isP ? 0 : 2048);               // [parity][1024]
    float* outb = isP ? (out + (size_t)TQ * 2048) : out;
    const int ghTok0 = isP ? TQ : 0;

    // elems: e0=(0,u0); e1= u0? (1,u0-1):(0,1024); e2=(0,u0+1); e3=(1,u0)
    int dirE[4], rowE[4];
    bool stE1;
    dirE[0] = 0; rowE[0] = u0;
    if (u0 == 0) { dirE[1] = 0; rowE[1] = 1024;   stE1 = false; }
    else         { dirE[1] = 1; rowE[1] = u0 - 1; stE1 = true;  }
    dirE[2] = 0; rowE[2] = u0 + 1;
    dirE[3] = 1; rowE[3] = u0;

    // register-resident Wih rows (k-split: lane l holds k = 4l + 256i + m)
    float wreg[12][16], breg[12];
#pragma unroll
    for (int e = 0; e < 4; e++) {
        const float* W  = dirE[e] ? Wih_b : Wih_f;
        const float* bb = dirE[e] ? bih_b : bih_f;
#pragma unroll
        for (int g = 0; g < 3; g++) {
            const float* wr = W + (size_t)(g * HH + rowE[e]) * H;
#pragma unroll
            for (int i = 0; i < 4; i++) {
                float4 w4 = *(const float4*)(wr + i * 256 + lane * 4);
                wreg[e*3+g][i*4+0] = w4.x; wreg[e*3+g][i*4+1] = w4.y;
                wreg[e*3+g][i*4+2] = w4.z; wreg[e*3+g][i*4+3] = w4.w;
            }
            breg[e*3+g] = bb[g * HH + rowE[e]];
        }
    }
    float wregX[3][16], bregX[3];
    if (extra) {
#pragma unroll
        for (int g = 0; g < 3; g++) {
            const float* wr = Wih_b + (size_t)(g * HH + 1023) * H;
#pragma unroll
            for (int i = 0; i < 4; i++) {
                float4 w4 = *(const float4*)(wr + i * 256 + lane * 4);
                wregX[g][i*4+0] = w4.x; wregX[g][i*4+1] = w4.y;
                wregX[g][i*4+2] = w4.z; wregX[g][i*4+3] = w4.w;
            }
            bregX[g] = bih_b[g * HH + 1023];
        }
    }

    // wave-uniform gh/h0 offsets
    size_t ghoff[4];
    int h0col[4];
#pragma unroll
    for (int e = 0; e < 4; e++) {
        ghoff[e] = (dirE[e] ? GH_ELEMS : (size_t)0) + (size_t)rowE[e];
        h0col[e] = dirE[e] ? (1025 + rowE[e]) : rowE[e];
    }
    const size_t ghoffX = GH_ELEMS + 1023;

    auto ldgh = [&](int tok, float gh[12], float h0[4], float ghX[3], float& h0X) {
        size_t tb = (size_t)(ghTok0 + tok) * N3;
#pragma unroll
        for (int e = 0; e < 4; e++) {
#pragma unroll
            for (int g = 0; g < 3; g++)
                gh[e*3+g] = ghf[ghoff[e] + tb + (size_t)g * HH];
            h0[e] = emb[(size_t)tok * 2048 + h0col[e]];
        }
        if (extra) {
#pragma unroll
            for (int g = 0; g < 3; g++) ghX[g] = ghf[ghoffX + tb + (size_t)g * HH];
            h0X = fsp ? fsp[tok] : 0.f;
        }
    };

    float ghc[12], h0c[4], ghcX[3]; float h0X = 0.f;
    float ghn[12], h0n[4], ghnX[3]; float h0nX = 0.f;
    ldgh(0, ghc, h0c, ghcX, h0X);

    for (int t = 0; t < nT; t++) {
        const int par = t & 1;
        float x[16];
        if (t) {
            // ---- detect: poll the data directly (2 x 16B granules/thread) --
            const unsigned tag = (unsigned)t;
            const ull* rb = cm + (size_t)((t + 1) & 1) * 1024;
            const ull* p0 = rb + 4 * tid;
            const ull* p1 = p0 + 2;
            u32x4 a, b;
            load2t(p0, p1, a, b);
            while (!((a[1] == tag) & (a[3] == tag) & (b[1] == tag) & (b[3] == tag))) {
                load2t(p0, p1, a, b);
            }
            float4 xv4;
            xv4.x = __uint_as_float(a[0]); xv4.y = __uint_as_float(a[2]);
            xv4.z = __uint_as_float(b[0]); xv4.w = __uint_as_float(b[2]);
            *(float4*)&xs[par][4 * tid] = xv4;
            __syncthreads();
#pragma unroll
            for (int i = 0; i < 4; i++) {
                float4 xv = *(const float4*)&xs[par][i * 256 + 4 * lane];
                x[i*4+0] = xv.x; x[i*4+1] = xv.y; x[i*4+2] = xv.z; x[i*4+3] = xv.w;
            }
        } else {
#pragma unroll
            for (int k = 0; k < 16; k++) x[k] = 0.f;
        }

        // ---- prefetch next gh/h0 AFTER detect (hides under compute) --------
        const bool more = (t + 1) < nT;
        if (more) ldgh(t + 1, ghn, h0n, ghnX, h0nX);

        // ---- dots + butterfly reduce ---------------------------------------
        float acc[12], accX[3];
#pragma unroll
        for (int r = 0; r < 12; r++) {
            float s = 0.f;
#pragma unroll
            for (int i = 0; i < 16; i++) s += wreg[r][i] * x[i];
            acc[r] = s;
        }
        if (extra) {
#pragma unroll
            for (int g = 0; g < 3; g++) {
                float s = 0.f;
#pragma unroll
                for (int i = 0; i < 16; i++) s += wregX[g][i] * x[i];
                accX[g] = s;
            }
        }
#pragma unroll
        for (int off = 32; off > 0; off >>= 1) {
#pragma unroll
            for (int r = 0; r < 12; r++) acc[r] += __shfl_xor(acc[r], off, 64);
            if (extra) {
#pragma unroll
                for (int g = 0; g < 3; g++) accX[g] += __shfl_xor(accX[g], off, 64);
            }
        }

        // ---- gates (redundant across lanes) --------------------------------
        float y[4];
#pragma unroll
        for (int e = 0; e < 4; e++) {
            float rr = sigm(acc[e*3+0] + breg[e*3+0] + ghc[e*3+0]);
            float zz = sigm(acc[e*3+1] + breg[e*3+1] + ghc[e*3+1]);
            float nn = fast_tanh(acc[e*3+2] + breg[e*3+2] + rr * ghc[e*3+2]);
            y[e] = (1.f - zz) * nn + zz * h0c[e];
        }

        // ---- publish (no ack) then out-stores ------------------------------
        if (lane == 0) {
            u32x4 pk;
            pk[0] = __float_as_uint(y[0] + y[1]); pk[1] = (unsigned)(t + 1);
            pk[2] = __float_as_uint(y[2] + y[3]); pk[3] = (unsigned)(t + 1);
            store1g(cm + (size_t)par * 1024 + u0, pk);

            size_t ob = (size_t)t * 2048;
            outb[ob + u0]        = y[0];
            outb[ob + u0 + 1]    = y[2];
            if (stE1) outb[ob + 1023 + u0] = y[1];
            outb[ob + 1024 + u0] = y[3];
            if (extra) {
                float rr = sigm(accX[0] + bregX[0] + ghcX[0]);
                float zz = sigm(accX[1] + bregX[1] + ghcX[1]);
                float nn = fast_tanh(accX[2] + bregX[2] + rr * ghcX[2]);
                outb[ob + 2047] = (1.f - zz) * nn + zz * h0X;
            }
        }

        if (more) {
#pragma unroll
            for (int r = 0; r < 12; r++) ghc[r] = ghn[r];
#pragma unroll
            for (int e = 0; e < 4; e++) h0c[e] = h0n[e];
#pragma unroll
            for (int g = 0; g < 3; g++) ghcX[g] = ghnX[g];
            h0X = h0nX;
        }
    }
}

extern "C" void kernel_launch(void* const* d_in, const int* in_sizes, int n_in,
                              void* d_out, int out_size, void* d_ws, size_t ws_size,
                              hipStream_t stream) {
    const float* eq    = (const float*)d_in[0];
    const float* ep    = (const float*)d_in[1];
    const float* fs    = (const float*)d_in[2];
    const float* fe    = (const float*)d_in[3];
    const float* Wih_f = (const float*)d_in[4];
    const float* Whh_f = (const float*)d_in[5];
    const float* bih_f = (const float*)d_in[6];
    const float* bhh_f = (const float*)d_in[7];
    const float* Wih_b = (const float*)d_in[8];
    const float* Whh_b = (const float*)d_in[9];
    const float* bih_b = (const float*)d_in[10];
    const float* bhh_b = (const float*)d_in[11];
    float* out = (float*)d_out;

    float* ghf = (float*)d_ws;
    float* ghb = ghf + GH_ELEMS;
    size_t off = ((2 * GH_ELEMS * sizeof(float)) + 4095) & ~(size_t)4095;
    ull* comm = (ull*)((char*)d_ws + off);   // 2 chains x 2 par x 1024 x 8B = 32KB

    hipMemsetAsync(comm, 0, (size_t)4096 * sizeof(ull), stream);

    dim3 ggrid((N3 + 127) / 128, MTOT / 128, 2);
    gh_gemm<<<ggrid, 256, 0, stream>>>(eq, ep, fs, fe, Whh_f, bhh_f, Whh_b, bhh_b, ghf, ghb);

    bigru_scan<<<dim3(NBLK_P + NBLK_Q), dim3(256), 0, stream>>>(
        eq, ep, fs, Wih_f, bih_f, Wih_b, bih_b, ghf, comm, out);
}